// Round 10
// baseline (1737.598 us; speedup 1.0000x reference)
//
#include <hip/hip_runtime.h>
#include <math.h>
#include <stdint.h>

// Autoregressive flow via MFMA (bf16), round 10.
// vs r9 (passing but spilling at launch_bounds(256,3)): shrink transient reg
// peak to fit 3 waves/SIMD without scratch spills:
//  - ks2 A-frags built SEQUENTIALLY (1 live quad, not 4 -> peak -16 regs)
//  - b1 as MLP1 C-operand init (8 persistent regs, kills B1F MFMAs/loads)
//  - W2 frag hoisted to persistent regs (loop-invariant)
// Everything else identical to the numerically-validated r9 kernel.

typedef short bf16x8 __attribute__((ext_vector_type(8)));
typedef float f32x4  __attribute__((ext_vector_type(4)));
typedef unsigned int u32x2 __attribute__((ext_vector_type(2)));

// workspace layout (shorts)
#define OFF_RZN 0          // [192][64]   Whh rows (R,Z,N), prescaled
#define OFF_KS2 12288      // [4][4][16][4]  gate ks2 lo-half frags (1024)
#define OFF_B1F 13312      // [2][16][4]     b1 frags (unused by r10 kernel)
#define OFF_W1F 13440      // [4][64][8]     W1 frags, frag-major (2048)
#define OFF_W2F 15488      // [64][8]        W2 frag (rows 4->16 zero-pad) (512)
#define WS_TOT  16000

#define WTAB_N  3200       // shorts staged to LDS (OFF_KS2..OFF_W2F: KS2|B1F|W1F)
#define HLW 104            // per-wave h row stride (shorts)
#define XYW 28             // x/y row stride (floats)

#define SCL_RZ (-1.4426950408889634f)   // -log2(e)
#define SCL_NI ( 2.8853900817779268f)   // 2*log2(e)

__device__ __forceinline__ short f2bf(float f) {
    union { float f; uint32_t u; } v; v.f = f;
    uint32_t r = v.u + 0x7fffu + ((v.u >> 16) & 1u);
    return (short)(r >> 16);
}
__device__ __forceinline__ uint32_t cvtpk(float lo, float hi) {
    uint32_t r;
    asm("v_cvt_pk_bf16_f32 %0, %1, %2" : "=v"(r) : "v"(lo), "v"(hi));
    return r;
}
__device__ __forceinline__ float rcpf(float x) { return __builtin_amdgcn_rcpf(x); }
__device__ __forceinline__ float softplusf(float x) {
    return fmaxf(x, 0.f) + __logf(1.f + __expf(-fabsf(x)));
}
__device__ __forceinline__ bf16x8 fraglo(u32x2 lo) {
    union { bf16x8 v; uint32_t u[4]; } f;
    f.u[0] = lo[0]; f.u[1] = lo[1]; f.u[2] = 0u; f.u[3] = 0u;
    return f.v;
}

// ---------------- weight prep (unchanged from r8/r9) ----------------
__global__ void prep_kernel(const float* __restrict__ Wih, const float* __restrict__ Whh,
                            const float* __restrict__ bih, const float* __restrict__ bhh,
                            const float* __restrict__ W1, const float* __restrict__ W2,
                            const float* __restrict__ b1,
                            short* __restrict__ wsw) {
    int idx = blockIdx.x * blockDim.x + threadIdx.x;
    if (idx >= WS_TOT) return;
    float v = 0.f;
    if (idx < OFF_KS2) {
        int row = idx >> 6;
        v = Whh[idx] * ((row < 128) ? SCL_RZ : SCL_NI);
    } else if (idx < OFF_B1F) {
        int i = idx - OFF_KS2;
        int s = i >> 8, mg = (i >> 6) & 3, ln = (i >> 2) & 15, j = i & 3;
        int r = mg * 16 + ln;
        if (s == 0) {            // R
            if (j == 0) v = Wih[2 * r];
            else if (j == 1) v = Wih[2 * r + 1];
            else if (j == 2) v = bih[r] + bhh[r];
        } else if (s == 1) {     // Z
            int row = 64 + r;
            if (j == 0) v = Wih[2 * row];
            else if (j == 1) v = Wih[2 * row + 1];
            else if (j == 2) v = bih[row] + bhh[row];
        } else if (s == 2) {     // N (bhh_n only; r-scaled inside tanh arg)
            if (j == 2) v = bhh[128 + r];
        } else {                 // I (i_n = Wih_n . y + bih_n)
            int row = 128 + r;
            if (j == 0) v = Wih[2 * row];
            else if (j == 1) v = Wih[2 * row + 1];
            else if (j == 2) v = bih[row];
        }
        v *= (s < 2) ? SCL_RZ : SCL_NI;
    } else if (idx < OFF_W1F) {
        int i = idx - OFF_B1F;
        int mt = (i >> 6) & 1, ln = (i >> 2) & 15, j = i & 3;
        v = (j == 2) ? b1[mt * 16 + ln] : 0.f;       // unused by r10 kernel
    } else if (idx < OFF_W2F) {
        int i = idx - OFF_W1F;
        int fi = i >> 9, l = (i >> 3) & 63, j = i & 7;
        int mt = fi >> 1, ks = fi & 1;
        v = W1[(mt * 16 + (l & 15)) * 64 + ks * 32 + ((l >> 4) & 3) * 8 + j];
    } else {
        int i = idx - OFF_W2F;
        int l = (i >> 3) & 63, j = i & 7;
        int lnn = l & 15;
        v = (lnn < 4) ? W2[lnn * 32 + ((l >> 4) & 3) * 8 + j] : 0.f;
    }
    wsw[idx] = f2bf(v);
}

// ---------------- main kernel: 4 waves/block, 16 rows/wave, 3 blocks/CU ----------------
__global__ __launch_bounds__(256, 3)
void arflow10(const float* __restrict__ y_tm1,
              const float* __restrict__ z,
              const float* __restrict__ x,
              const float* __restrict__ b1,
              const float* __restrict__ b2,
              const short* __restrict__ wsw,
              float* __restrict__ out,
              int B, int T)
{
    __shared__ __align__(16) float XY[64 * XYW];      //  7168 B (x, overwritten by y)
    __shared__ __align__(16) short HL[4][16 * HLW];   // 13312 B (per-wave h + a)
    __shared__ __align__(16) short WTAB[WTAB_N];      //  6400 B (KS2|B1F|W1F)

    const int tid  = threadIdx.x;
    const int wave = tid >> 6;
    const int lane = tid & 63;
    const int g    = lane >> 4;
    const int ln   = lane & 15;
    const bool g0  = (g == 0);
    const int base = blockIdx.x * 64;
    const int rows = (B - base < 64) ? (B - base) : 64;
    const int NF4  = T >> 1;   // float4s per x-row

    // ---- stage x -> XY (coalesced) ----
    {
        const float4* xg = reinterpret_cast<const float4*>(x) + (size_t)base * NF4;
        const int tot = 64 * NF4;
        for (int i = tid; i < tot; i += 256) {
            float4 v = (i < rows * NF4) ? xg[i] : make_float4(0.f, 0.f, 0.f, 0.f);
            int r = i / NF4, c = i - r * NF4;
            *reinterpret_cast<float4*>(&XY[r * XYW + c * 4]) = v;
        }
    }
    // ---- stage WTAB (contiguous) ----
    {
        const uint4* src = reinterpret_cast<const uint4*>(wsw + OFF_KS2);
        uint4* dst = reinterpret_cast<uint4*>(WTAB);
        for (int i = tid; i < WTAB_N / 8; i += 256) dst[i] = src[i];
    }

    // ---- GRU weights -> VGPRs (96 regs, the deliberate budget item) ----
    bf16x8 wR[4][2], wZ[4][2], wN[4][2];
#pragma unroll
    for (int mg = 0; mg < 4; ++mg)
#pragma unroll
        for (int ks = 0; ks < 2; ++ks) {
            wR[mg][ks] = *reinterpret_cast<const bf16x8*>(wsw + ((      mg * 16 + ln) * 64 + ks * 32 + g * 8));
            wZ[mg][ks] = *reinterpret_cast<const bf16x8*>(wsw + ((64  + mg * 16 + ln) * 64 + ks * 32 + g * 8));
            wN[mg][ks] = *reinterpret_cast<const bf16x8*>(wsw + ((128 + mg * 16 + ln) * 64 + ks * 32 + g * 8));
        }
    // W2 frag hoisted (loop-invariant, 4 regs)
    bf16x8 w2f = *reinterpret_cast<const bf16x8*>(wsw + OFF_W2F + lane * 8);

    // b1 in D-layout as MLP1 C-operand init (8 persistent regs)
    f32x4 b1q[2];
#pragma unroll
    for (int mt = 0; mt < 2; ++mt) {
        float4 tv = reinterpret_cast<const float4*>(b1)[mt * 4 + g];
        b1q[mt][0] = tv.x; b1q[mt][1] = tv.y; b1q[mt][2] = tv.z; b1q[mt][3] = tv.w;
    }

    const float b20 = b2[0], b21 = b2[1], b22 = b2[2], b23 = b2[3];
    const f32x4 Z0 = {0.f, 0.f, 0.f, 0.f};

    // ---- init h (fp32, D-layout) and y; one batch row per lane ----
    const int gr = base + wave * 16 + ln;
    const bool ok = gr < B;
    float hpr[4][4];
    float2 y;
    short* hl = &HL[wave][0];
#pragma unroll
    for (int mg = 0; mg < 4; ++mg) {
        float4 zv = ok ? reinterpret_cast<const float4*>(z)[(size_t)gr * 16 + mg * 4 + g]
                       : make_float4(0.f, 0.f, 0.f, 0.f);
        hpr[mg][0] = zv.x; hpr[mg][1] = zv.y; hpr[mg][2] = zv.z; hpr[mg][3] = zv.w;
    }
    y = ok ? reinterpret_cast<const float2*>(y_tm1)[gr] : make_float2(0.f, 0.f);

#pragma unroll
    for (int mg = 0; mg < 4; ++mg) {
        uint2 pk;
        pk.x = cvtpk(hpr[mg][0], hpr[mg][1]);
        pk.y = cvtpk(hpr[mg][2], hpr[mg][3]);
        *reinterpret_cast<uint2*>(&hl[ln * HLW + mg * 16 + g * 4]) = pk;
    }
    bf16x8 hb[2];
#pragma unroll
    for (int ks = 0; ks < 2; ++ks)
        hb[ks] = *reinterpret_cast<const bf16x8*>(&hl[ln * HLW + ks * 32 + g * 8]);

    __syncthreads();

    const uint32_t onepk = g0 ? 0x00003F80u : 0u;   // bf16(1.0) at elem slot 2
    // lo-half frag pointers (u32x2 = 4 shorts); g>0 lanes read don't-care data
    const volatile u32x2*  k2q = reinterpret_cast<const volatile u32x2*>(WTAB) + ln;
    const volatile bf16x8* w1q = reinterpret_cast<const volatile bf16x8*>(WTAB + (OFF_W1F - OFF_KS2)) + lane;

    for (int t = 0; t < T; ++t) {
        // ks2 B-frag: k=0..2 = [y.x, y.y, 1] on g==0 lanes, else 0
        bf16x8 yb;
        {
            uint32_t ypk = cvtpk(y.x, y.y);
            union { bf16x8 v; uint32_t u[4]; } yu;
            yu.u[0] = g0 ? ypk : 0u;
            yu.u[1] = onepk;
            yu.u[2] = 0u; yu.u[3] = 0u;
            yb = yu.v;
        }

        // ---- GRU ----
#pragma unroll
        for (int mg = 0; mg < 4; ++mg) {
            // ks2 frags built sequentially: one live quad at a time
            f32x4 aR = __builtin_amdgcn_mfma_f32_16x16x32_bf16(fraglo(k2q[(0 * 4 + mg) * 16]), yb, Z0, 0, 0, 0);
            f32x4 aZ = __builtin_amdgcn_mfma_f32_16x16x32_bf16(fraglo(k2q[(1 * 4 + mg) * 16]), yb, Z0, 0, 0, 0);
            f32x4 aN = __builtin_amdgcn_mfma_f32_16x16x32_bf16(fraglo(k2q[(2 * 4 + mg) * 16]), yb, Z0, 0, 0, 0);
            f32x4 aI = __builtin_amdgcn_mfma_f32_16x16x32_bf16(fraglo(k2q[(3 * 4 + mg) * 16]), yb, Z0, 0, 0, 0);
            aR = __builtin_amdgcn_mfma_f32_16x16x32_bf16(wR[mg][0], hb[0], aR, 0, 0, 0);
            aZ = __builtin_amdgcn_mfma_f32_16x16x32_bf16(wZ[mg][0], hb[0], aZ, 0, 0, 0);
            aN = __builtin_amdgcn_mfma_f32_16x16x32_bf16(wN[mg][0], hb[0], aN, 0, 0, 0);
            aR = __builtin_amdgcn_mfma_f32_16x16x32_bf16(wR[mg][1], hb[1], aR, 0, 0, 0);
            aZ = __builtin_amdgcn_mfma_f32_16x16x32_bf16(wZ[mg][1], hb[1], aZ, 0, 0, 0);
            aN = __builtin_amdgcn_mfma_f32_16x16x32_bf16(wN[mg][1], hb[1], aN, 0, 0, 0);

            float hq[4];
#pragma unroll
            for (int q = 0; q < 4; ++q) {
                float r  = rcpf(1.f + exp2f(aR[q]));
                float u  = rcpf(1.f + exp2f(aZ[q]));
                float ee = exp2f(fmaf(r, aN[q], aI[q]));
                float nn = fmaf(-2.f, rcpf(ee + 1.f), 1.f);
                float hv = fmaf(u, hpr[mg][q] - nn, nn);   // (1-u)*n + u*h
                hpr[mg][q] = hv;
                hq[q] = hv;
            }
            uint2 pk;
            pk.x = cvtpk(hq[0], hq[1]);
            pk.y = cvtpk(hq[2], hq[3]);
            *reinterpret_cast<uint2*>(&hl[ln * HLW + mg * 16 + g * 4]) = pk;
        }

        // ---- re-read h' B-frags (MLP1 now, GRU next step) ----
        hb[0] = *reinterpret_cast<const bf16x8*>(&hl[ln * HLW +  0 + g * 8]);
        hb[1] = *reinterpret_cast<const bf16x8*>(&hl[ln * HLW + 32 + g * 8]);

        // ---- MLP1 via MFMA (b1 as C-operand init) ----
        f32x4 aM[2];
#pragma unroll
        for (int mt = 0; mt < 2; ++mt) {
            bf16x8 w0 = w1q[(mt * 2 + 0) * 64];
            bf16x8 w1 = w1q[(mt * 2 + 1) * 64];
            f32x4 a = __builtin_amdgcn_mfma_f32_16x16x32_bf16(w0, hb[0], b1q[mt], 0, 0, 0);
            aM[mt] = __builtin_amdgcn_mfma_f32_16x16x32_bf16(w1, hb[1], a, 0, 0, 0);
        }

        // ---- relu(a) -> hl cols 64..95, MLP2 via padded MFMA ----
#pragma unroll
        for (int mt = 0; mt < 2; ++mt) {
            uint2 pk;
            pk.x = cvtpk(fmaxf(aM[mt][0], 0.f), fmaxf(aM[mt][1], 0.f));
            pk.y = cvtpk(fmaxf(aM[mt][2], 0.f), fmaxf(aM[mt][3], 0.f));
            *reinterpret_cast<uint2*>(&hl[ln * HLW + 64 + mt * 16 + g * 4]) = pk;
        }
        f32x4 aD;
        {
            bf16x8 ab = *reinterpret_cast<const bf16x8*>(&hl[ln * HLW + 64 + g * 8]);
            aD = __builtin_amdgcn_mfma_f32_16x16x32_bf16(w2f, ab, Z0, 0, 0, 0);
        }

        // ---- flow update (aD valid on g==0; 0 on g>0 so y stays finite) ----
        {
            int rl = wave * 16 + ln;
            float2 xt = *reinterpret_cast<const float2*>(&XY[rl * XYW + t * 2]);
            float s0 = softplusf(aD[2] + b22) + 1e-6f;
            float s1 = softplusf(aD[3] + b23) + 1e-6f;
            y.x += (aD[0] + b20) + s0 * xt.x;
            y.y += (aD[1] + b21) + s1 * xt.y;
            if (g0)
                *reinterpret_cast<float2*>(&XY[rl * XYW + t * 2]) = y;
        }
    }

    __syncthreads();
    // ---- coalesced store XY -> out ----
    {
        float4* og = reinterpret_cast<float4*>(out) + (size_t)base * NF4;
        const int tot = 64 * NF4;
        for (int i = tid; i < tot; i += 256) {
            if (i < rows * NF4) {
                int r = i / NF4, c = i - r * NF4;
                og[i] = *reinterpret_cast<const float4*>(&XY[r * XYW + c * 4]);
            }
        }
    }
}

extern "C" void kernel_launch(void* const* d_in, const int* in_sizes, int n_in,
                              void* d_out, int out_size, void* d_ws, size_t ws_size,
                              hipStream_t stream) {
    const float* y_tm1 = (const float*)d_in[0];
    const float* z     = (const float*)d_in[1];
    const float* x     = (const float*)d_in[2];
    const float* Wih   = (const float*)d_in[3];
    const float* Whh   = (const float*)d_in[4];
    const float* bih   = (const float*)d_in[5];
    const float* bhh   = (const float*)d_in[6];
    const float* W1    = (const float*)d_in[7];
    const float* b1    = (const float*)d_in[8];
    const float* W2    = (const float*)d_in[9];
    const float* b2    = (const float*)d_in[10];
    float* out = (float*)d_out;
    short* wsw = (short*)d_ws;

    const int B = in_sizes[0] / 2;
    const int T = in_sizes[2] / in_sizes[0];

    hipLaunchKernelGGL(prep_kernel, dim3((WS_TOT + 255) / 256), dim3(256), 0, stream,
                       Wih, Whh, bih, bhh, W1, W2, b1, wsw);

    const int nblk = (B + 63) / 64;
    hipLaunchKernelGGL(arflow10, dim3(nblk), dim3(256), 0, stream,
                       y_tm1, z, x, b1, b2, wsw, out, B, T);
}

// Round 11
// 1344.067 us; speedup vs baseline: 1.2928x; 1.2928x over previous
//
#include <hip/hip_runtime.h>
#include <math.h>
#include <stdint.h>

// Autoregressive flow via MFMA (bf16), round 11.
// vs r10 (passing, but still scratch-spilling at launch_bounds(256,3)):
// eliminate the fp32 h shadow (hpr[4][4], 16 persistent VGPRs). The bf16
// D-layout h already lives in per-wave LDS (written every step at the lane's
// own address); the u*h blend now reads the old-h quad back from LDS
// (1 ds_read_b64 per mg) and unpacks bf16->f32 with shl/and. Live-set est.
// ~152 regs < 168 cap -> no spills. Precision: blend uses bf16-rounded h
// (h is already bf16-quantized for MFMA each step; extra error ~2e-3/step).

typedef short bf16x8 __attribute__((ext_vector_type(8)));
typedef float f32x4  __attribute__((ext_vector_type(4)));
typedef unsigned int u32x2 __attribute__((ext_vector_type(2)));

// workspace layout (shorts)
#define OFF_RZN 0          // [192][64]   Whh rows (R,Z,N), prescaled
#define OFF_KS2 12288      // [4][4][16][4]  gate ks2 lo-half frags (1024)
#define OFF_B1F 13312      // [2][16][4]     b1 frags (unused by r11 kernel)
#define OFF_W1F 13440      // [4][64][8]     W1 frags, frag-major (2048)
#define OFF_W2F 15488      // [64][8]        W2 frag (rows 4->16 zero-pad) (512)
#define WS_TOT  16000

#define WTAB_N  3200       // shorts staged to LDS (KS2|B1F|W1F)
#define HLW 104            // per-wave h row stride (shorts)
#define XYW 28             // x/y row stride (floats)

#define SCL_RZ (-1.4426950408889634f)   // -log2(e)
#define SCL_NI ( 2.8853900817779268f)   // 2*log2(e)

__device__ __forceinline__ short f2bf(float f) {
    union { float f; uint32_t u; } v; v.f = f;
    uint32_t r = v.u + 0x7fffu + ((v.u >> 16) & 1u);
    return (short)(r >> 16);
}
__device__ __forceinline__ uint32_t cvtpk(float lo, float hi) {
    uint32_t r;
    asm("v_cvt_pk_bf16_f32 %0, %1, %2" : "=v"(r) : "v"(lo), "v"(hi));
    return r;
}
__device__ __forceinline__ float rcpf(float x) { return __builtin_amdgcn_rcpf(x); }
__device__ __forceinline__ float softplusf(float x) {
    return fmaxf(x, 0.f) + __logf(1.f + __expf(-fabsf(x)));
}
__device__ __forceinline__ bf16x8 fraglo(u32x2 lo) {
    union { bf16x8 v; uint32_t u[4]; } f;
    f.u[0] = lo[0]; f.u[1] = lo[1]; f.u[2] = 0u; f.u[3] = 0u;
    return f.v;
}
__device__ __forceinline__ float bflo(uint32_t p) {   // low bf16 -> f32
    union { float f; uint32_t u; } v; v.u = p << 16; return v.f;
}
__device__ __forceinline__ float bfhi(uint32_t p) {   // high bf16 -> f32
    union { float f; uint32_t u; } v; v.u = p & 0xffff0000u; return v.f;
}

// ---------------- weight prep (unchanged from r8-r10) ----------------
__global__ void prep_kernel(const float* __restrict__ Wih, const float* __restrict__ Whh,
                            const float* __restrict__ bih, const float* __restrict__ bhh,
                            const float* __restrict__ W1, const float* __restrict__ W2,
                            const float* __restrict__ b1,
                            short* __restrict__ wsw) {
    int idx = blockIdx.x * blockDim.x + threadIdx.x;
    if (idx >= WS_TOT) return;
    float v = 0.f;
    if (idx < OFF_KS2) {
        int row = idx >> 6;
        v = Whh[idx] * ((row < 128) ? SCL_RZ : SCL_NI);
    } else if (idx < OFF_B1F) {
        int i = idx - OFF_KS2;
        int s = i >> 8, mg = (i >> 6) & 3, ln = (i >> 2) & 15, j = i & 3;
        int r = mg * 16 + ln;
        if (s == 0) {            // R
            if (j == 0) v = Wih[2 * r];
            else if (j == 1) v = Wih[2 * r + 1];
            else if (j == 2) v = bih[r] + bhh[r];
        } else if (s == 1) {     // Z
            int row = 64 + r;
            if (j == 0) v = Wih[2 * row];
            else if (j == 1) v = Wih[2 * row + 1];
            else if (j == 2) v = bih[row] + bhh[row];
        } else if (s == 2) {     // N (bhh_n only; r-scaled inside tanh arg)
            if (j == 2) v = bhh[128 + r];
        } else {                 // I (i_n = Wih_n . y + bih_n)
            int row = 128 + r;
            if (j == 0) v = Wih[2 * row];
            else if (j == 1) v = Wih[2 * row + 1];
            else if (j == 2) v = bih[row];
        }
        v *= (s < 2) ? SCL_RZ : SCL_NI;
    } else if (idx < OFF_W1F) {
        int i = idx - OFF_B1F;
        int mt = (i >> 6) & 1, ln = (i >> 2) & 15, j = i & 3;
        v = (j == 2) ? b1[mt * 16 + ln] : 0.f;       // unused by r11 kernel
    } else if (idx < OFF_W2F) {
        int i = idx - OFF_W1F;
        int fi = i >> 9, l = (i >> 3) & 63, j = i & 7;
        int mt = fi >> 1, ks = fi & 1;
        v = W1[(mt * 16 + (l & 15)) * 64 + ks * 32 + ((l >> 4) & 3) * 8 + j];
    } else {
        int i = idx - OFF_W2F;
        int l = (i >> 3) & 63, j = i & 7;
        int lnn = l & 15;
        v = (lnn < 4) ? W2[lnn * 32 + ((l >> 4) & 3) * 8 + j] : 0.f;
    }
    wsw[idx] = f2bf(v);
}

// ---------------- main kernel: 4 waves/block, 16 rows/wave, 3 blocks/CU ----------------
__global__ __launch_bounds__(256, 3)
void arflow11(const float* __restrict__ y_tm1,
              const float* __restrict__ z,
              const float* __restrict__ x,
              const float* __restrict__ b1,
              const float* __restrict__ b2,
              const short* __restrict__ wsw,
              float* __restrict__ out,
              int B, int T)
{
    __shared__ __align__(16) float XY[64 * XYW];      //  7168 B (x, overwritten by y)
    __shared__ __align__(16) short HL[4][16 * HLW];   // 13312 B (per-wave h + a)
    __shared__ __align__(16) short WTAB[WTAB_N];      //  6400 B (KS2|B1F|W1F)

    const int tid  = threadIdx.x;
    const int wave = tid >> 6;
    const int lane = tid & 63;
    const int g    = lane >> 4;
    const int ln   = lane & 15;
    const bool g0  = (g == 0);
    const int base = blockIdx.x * 64;
    const int rows = (B - base < 64) ? (B - base) : 64;
    const int NF4  = T >> 1;   // float4s per x-row

    // ---- stage x -> XY (coalesced) ----
    {
        const float4* xg = reinterpret_cast<const float4*>(x) + (size_t)base * NF4;
        const int tot = 64 * NF4;
        for (int i = tid; i < tot; i += 256) {
            float4 v = (i < rows * NF4) ? xg[i] : make_float4(0.f, 0.f, 0.f, 0.f);
            int r = i / NF4, c = i - r * NF4;
            *reinterpret_cast<float4*>(&XY[r * XYW + c * 4]) = v;
        }
    }
    // ---- stage WTAB (contiguous) ----
    {
        const uint4* src = reinterpret_cast<const uint4*>(wsw + OFF_KS2);
        uint4* dst = reinterpret_cast<uint4*>(WTAB);
        for (int i = tid; i < WTAB_N / 8; i += 256) dst[i] = src[i];
    }

    // ---- GRU weights -> VGPRs/AGPRs (96 regs, the deliberate budget item) ----
    bf16x8 wR[4][2], wZ[4][2], wN[4][2];
#pragma unroll
    for (int mg = 0; mg < 4; ++mg)
#pragma unroll
        for (int ks = 0; ks < 2; ++ks) {
            wR[mg][ks] = *reinterpret_cast<const bf16x8*>(wsw + ((      mg * 16 + ln) * 64 + ks * 32 + g * 8));
            wZ[mg][ks] = *reinterpret_cast<const bf16x8*>(wsw + ((64  + mg * 16 + ln) * 64 + ks * 32 + g * 8));
            wN[mg][ks] = *reinterpret_cast<const bf16x8*>(wsw + ((128 + mg * 16 + ln) * 64 + ks * 32 + g * 8));
        }
    // W2 frag hoisted (loop-invariant, 4 regs)
    bf16x8 w2f = *reinterpret_cast<const bf16x8*>(wsw + OFF_W2F + lane * 8);

    // b1 in D-layout as MLP1 C-operand init (8 persistent regs)
    f32x4 b1q[2];
#pragma unroll
    for (int mt = 0; mt < 2; ++mt) {
        float4 tv = reinterpret_cast<const float4*>(b1)[mt * 4 + g];
        b1q[mt][0] = tv.x; b1q[mt][1] = tv.y; b1q[mt][2] = tv.z; b1q[mt][3] = tv.w;
    }

    const float b20 = b2[0], b21 = b2[1], b22 = b2[2], b23 = b2[3];
    const f32x4 Z0 = {0.f, 0.f, 0.f, 0.f};

    // ---- init h (bf16 -> LDS only, no fp32 shadow) and y ----
    const int gr = base + wave * 16 + ln;
    const bool ok = gr < B;
    float2 y;
    short* hl = &HL[wave][0];
#pragma unroll
    for (int mg = 0; mg < 4; ++mg) {
        float4 zv = ok ? reinterpret_cast<const float4*>(z)[(size_t)gr * 16 + mg * 4 + g]
                       : make_float4(0.f, 0.f, 0.f, 0.f);
        uint2 pk;
        pk.x = cvtpk(zv.x, zv.y);
        pk.y = cvtpk(zv.z, zv.w);
        *reinterpret_cast<uint2*>(&hl[ln * HLW + mg * 16 + g * 4]) = pk;
    }
    y = ok ? reinterpret_cast<const float2*>(y_tm1)[gr] : make_float2(0.f, 0.f);

    bf16x8 hb[2];
#pragma unroll
    for (int ks = 0; ks < 2; ++ks)
        hb[ks] = *reinterpret_cast<const bf16x8*>(&hl[ln * HLW + ks * 32 + g * 8]);

    __syncthreads();

    const uint32_t onepk = g0 ? 0x00003F80u : 0u;   // bf16(1.0) at elem slot 2
    // lo-half frag pointers (u32x2 = 4 shorts); g>0 lanes read don't-care data
    const volatile u32x2*  k2q = reinterpret_cast<const volatile u32x2*>(WTAB) + ln;
    const volatile bf16x8* w1q = reinterpret_cast<const volatile bf16x8*>(WTAB + (OFF_W1F - OFF_KS2)) + lane;

    for (int t = 0; t < T; ++t) {
        // ks2 B-frag: k=0..2 = [y.x, y.y, 1] on g==0 lanes, else 0
        bf16x8 yb;
        {
            uint32_t ypk = cvtpk(y.x, y.y);
            union { bf16x8 v; uint32_t u[4]; } yu;
            yu.u[0] = g0 ? ypk : 0u;
            yu.u[1] = onepk;
            yu.u[2] = 0u; yu.u[3] = 0u;
            yb = yu.v;
        }

        // ---- GRU ----
#pragma unroll
        for (int mg = 0; mg < 4; ++mg) {
            // ks2 frags built sequentially: one live quad at a time
            f32x4 aR = __builtin_amdgcn_mfma_f32_16x16x32_bf16(fraglo(k2q[(0 * 4 + mg) * 16]), yb, Z0, 0, 0, 0);
            f32x4 aZ = __builtin_amdgcn_mfma_f32_16x16x32_bf16(fraglo(k2q[(1 * 4 + mg) * 16]), yb, Z0, 0, 0, 0);
            f32x4 aN = __builtin_amdgcn_mfma_f32_16x16x32_bf16(fraglo(k2q[(2 * 4 + mg) * 16]), yb, Z0, 0, 0, 0);
            f32x4 aI = __builtin_amdgcn_mfma_f32_16x16x32_bf16(fraglo(k2q[(3 * 4 + mg) * 16]), yb, Z0, 0, 0, 0);
            aR = __builtin_amdgcn_mfma_f32_16x16x32_bf16(wR[mg][0], hb[0], aR, 0, 0, 0);
            aZ = __builtin_amdgcn_mfma_f32_16x16x32_bf16(wZ[mg][0], hb[0], aZ, 0, 0, 0);
            aN = __builtin_amdgcn_mfma_f32_16x16x32_bf16(wN[mg][0], hb[0], aN, 0, 0, 0);
            aR = __builtin_amdgcn_mfma_f32_16x16x32_bf16(wR[mg][1], hb[1], aR, 0, 0, 0);
            aZ = __builtin_amdgcn_mfma_f32_16x16x32_bf16(wZ[mg][1], hb[1], aZ, 0, 0, 0);
            aN = __builtin_amdgcn_mfma_f32_16x16x32_bf16(wN[mg][1], hb[1], aN, 0, 0, 0);

            // old h (bf16, this lane's own D-layout quad) from LDS
            u32x2 oh = *reinterpret_cast<const u32x2*>(&hl[ln * HLW + mg * 16 + g * 4]);
            float hold[4];
            hold[0] = bflo(oh[0]); hold[1] = bfhi(oh[0]);
            hold[2] = bflo(oh[1]); hold[3] = bfhi(oh[1]);

            float hq[4];
#pragma unroll
            for (int q = 0; q < 4; ++q) {
                float r  = rcpf(1.f + exp2f(aR[q]));
                float u  = rcpf(1.f + exp2f(aZ[q]));
                float ee = exp2f(fmaf(r, aN[q], aI[q]));
                float nn = fmaf(-2.f, rcpf(ee + 1.f), 1.f);
                hq[q] = fmaf(u, hold[q] - nn, nn);   // (1-u)*n + u*h
            }
            uint2 pk;
            pk.x = cvtpk(hq[0], hq[1]);
            pk.y = cvtpk(hq[2], hq[3]);
            *reinterpret_cast<uint2*>(&hl[ln * HLW + mg * 16 + g * 4]) = pk;
        }

        // ---- re-read h' B-frags (MLP1 now, GRU next step) ----
        hb[0] = *reinterpret_cast<const bf16x8*>(&hl[ln * HLW +  0 + g * 8]);
        hb[1] = *reinterpret_cast<const bf16x8*>(&hl[ln * HLW + 32 + g * 8]);

        // ---- MLP1 via MFMA (b1 as C-operand init) ----
        f32x4 aM[2];
#pragma unroll
        for (int mt = 0; mt < 2; ++mt) {
            bf16x8 w0 = w1q[(mt * 2 + 0) * 64];
            bf16x8 w1 = w1q[(mt * 2 + 1) * 64];
            f32x4 a = __builtin_amdgcn_mfma_f32_16x16x32_bf16(w0, hb[0], b1q[mt], 0, 0, 0);
            aM[mt] = __builtin_amdgcn_mfma_f32_16x16x32_bf16(w1, hb[1], a, 0, 0, 0);
        }

        // ---- relu(a) -> hl cols 64..95, MLP2 via padded MFMA ----
#pragma unroll
        for (int mt = 0; mt < 2; ++mt) {
            uint2 pk;
            pk.x = cvtpk(fmaxf(aM[mt][0], 0.f), fmaxf(aM[mt][1], 0.f));
            pk.y = cvtpk(fmaxf(aM[mt][2], 0.f), fmaxf(aM[mt][3], 0.f));
            *reinterpret_cast<uint2*>(&hl[ln * HLW + 64 + mt * 16 + g * 4]) = pk;
        }
        f32x4 aD;
        {
            bf16x8 ab = *reinterpret_cast<const bf16x8*>(&hl[ln * HLW + 64 + g * 8]);
            aD = __builtin_amdgcn_mfma_f32_16x16x32_bf16(w2f, ab, Z0, 0, 0, 0);
        }

        // ---- flow update (aD valid on g==0; 0 on g>0 so y stays finite) ----
        {
            int rl = wave * 16 + ln;
            float2 xt = *reinterpret_cast<const float2*>(&XY[rl * XYW + t * 2]);
            float s0 = softplusf(aD[2] + b22) + 1e-6f;
            float s1 = softplusf(aD[3] + b23) + 1e-6f;
            y.x += (aD[0] + b20) + s0 * xt.x;
            y.y += (aD[1] + b21) + s1 * xt.y;
            if (g0)
                *reinterpret_cast<float2*>(&XY[rl * XYW + t * 2]) = y;
        }
    }

    __syncthreads();
    // ---- coalesced store XY -> out ----
    {
        float4* og = reinterpret_cast<float4*>(out) + (size_t)base * NF4;
        const int tot = 64 * NF4;
        for (int i = tid; i < tot; i += 256) {
            if (i < rows * NF4) {
                int r = i / NF4, c = i - r * NF4;
                og[i] = *reinterpret_cast<const float4*>(&XY[r * XYW + c * 4]);
            }
        }
    }
}

extern "C" void kernel_launch(void* const* d_in, const int* in_sizes, int n_in,
                              void* d_out, int out_size, void* d_ws, size_t ws_size,
                              hipStream_t stream) {
    const float* y_tm1 = (const float*)d_in[0];
    const float* z     = (const float*)d_in[1];
    const float* x     = (const float*)d_in[2];
    const float* Wih   = (const float*)d_in[3];
    const float* Whh   = (const float*)d_in[4];
    const float* bih   = (const float*)d_in[5];
    const float* bhh   = (const float*)d_in[6];
    const float* W1    = (const float*)d_in[7];
    const float* b1    = (const float*)d_in[8];
    const float* W2    = (const float*)d_in[9];
    const float* b2    = (const float*)d_in[10];
    float* out = (float*)d_out;
    short* wsw = (short*)d_ws;

    const int B = in_sizes[0] / 2;
    const int T = in_sizes[2] / in_sizes[0];

    hipLaunchKernelGGL(prep_kernel, dim3((WS_TOT + 255) / 256), dim3(256), 0, stream,
                       Wih, Whh, bih, bhh, W1, W2, b1, wsw);

    const int nblk = (B + 63) / 64;
    hipLaunchKernelGGL(arflow11, dim3(nblk), dim3(256), 0, stream,
                       y_tm1, z, x, b1, b2, wsw, out, B, T);
}

// Round 12
// 1231.655 us; speedup vs baseline: 1.4108x; 1.0913x over previous
//
#include <hip/hip_runtime.h>
#include <math.h>
#include <stdint.h>

// Autoregressive flow via MFMA (bf16), round 12.
// vs r11 (passing, absmax 0.0625, but still spilling at launch_bounds(256,3)):
// split weight storage: R,Z gate weights stay in VGPRs (64 regs); N gate
// weights move to LDS in frag-major layout (lane*16B linear -> dense
// conflict-free ds_read_b128, 8 reads/step, volatile). Peak live-set estimate
// ~142 regs < 168 (3 waves/SIMD cap) with real margin -> no scratch spills.
// All else identical to r11: LDS-resident bf16 h (no fp32 shadow), sequential
// ks2 frags, b1 as MLP1 C-operand, hoisted W2 frag, log2e prescale
// (sigmoid = rcp(1+exp2(acc)), tanh = 1 - 2*rcp(exp2(acc)+1)).

typedef short bf16x8 __attribute__((ext_vector_type(8)));
typedef float f32x4  __attribute__((ext_vector_type(4)));
typedef unsigned int u32x2 __attribute__((ext_vector_type(2)));

// workspace layout (shorts)
#define OFF_RZ  0          // [128][64]      Whh rows (R,Z) row-major, prescaled
#define OFF_NF  8192       // [4][2][64][8]  N-gate frags, frag-major, prescaled
#define OFF_KS2 12288      // [4][4][16][4]  gate ks2 lo-half frags (1024)
#define OFF_B1F 13312      // [2][16][4]     (unused in-kernel; kept for layout)
#define OFF_W1F 13440      // [4][64][8]     W1 frags, frag-major (2048)
#define OFF_W2F 15488      // [64][8]        W2 frag (rows 4->16 zero-pad) (512)
#define WS_TOT  16000

#define WTAB_N  7808       // shorts staged to LDS (OFF_NF..WS_TOT)
#define HLW 104            // per-wave h row stride (shorts)
#define XYW 28             // x/y row stride (floats)

#define SCL_RZ (-1.4426950408889634f)   // -log2(e)
#define SCL_NI ( 2.8853900817779268f)   // 2*log2(e)

__device__ __forceinline__ short f2bf(float f) {
    union { float f; uint32_t u; } v; v.f = f;
    uint32_t r = v.u + 0x7fffu + ((v.u >> 16) & 1u);
    return (short)(r >> 16);
}
__device__ __forceinline__ uint32_t cvtpk(float lo, float hi) {
    uint32_t r;
    asm("v_cvt_pk_bf16_f32 %0, %1, %2" : "=v"(r) : "v"(lo), "v"(hi));
    return r;
}
__device__ __forceinline__ float rcpf(float x) { return __builtin_amdgcn_rcpf(x); }
__device__ __forceinline__ float softplusf(float x) {
    return fmaxf(x, 0.f) + __logf(1.f + __expf(-fabsf(x)));
}
__device__ __forceinline__ bf16x8 fraglo(u32x2 lo) {
    union { bf16x8 v; uint32_t u[4]; } f;
    f.u[0] = lo[0]; f.u[1] = lo[1]; f.u[2] = 0u; f.u[3] = 0u;
    return f.v;
}
__device__ __forceinline__ float bflo(uint32_t p) {   // low bf16 -> f32
    union { float f; uint32_t u; } v; v.u = p << 16; return v.f;
}
__device__ __forceinline__ float bfhi(uint32_t p) {   // high bf16 -> f32
    union { float f; uint32_t u; } v; v.u = p & 0xffff0000u; return v.f;
}

// ---------------- weight prep ----------------
__global__ void prep_kernel(const float* __restrict__ Wih, const float* __restrict__ Whh,
                            const float* __restrict__ bih, const float* __restrict__ bhh,
                            const float* __restrict__ W1, const float* __restrict__ W2,
                            const float* __restrict__ b1,
                            short* __restrict__ wsw) {
    int idx = blockIdx.x * blockDim.x + threadIdx.x;
    if (idx >= WS_TOT) return;
    float v = 0.f;
    if (idx < OFF_NF) {
        v = Whh[idx] * SCL_RZ;                       // R,Z rows 0..127 row-major
    } else if (idx < OFF_KS2) {
        int i = idx - OFF_NF;
        int grp = i >> 9, l = (i >> 3) & 63, j = i & 7;   // grp = mg*2+ks
        int mg = grp >> 1, ks = grp & 1;
        int lnn = l & 15, gg = (l >> 4) & 3;
        v = Whh[(128 + mg * 16 + lnn) * 64 + ks * 32 + gg * 8 + j] * SCL_NI;
    } else if (idx < OFF_B1F) {
        int i = idx - OFF_KS2;
        int s = i >> 8, mg = (i >> 6) & 3, ln = (i >> 2) & 15, j = i & 3;
        int r = mg * 16 + ln;
        if (s == 0) {            // R
            if (j == 0) v = Wih[2 * r];
            else if (j == 1) v = Wih[2 * r + 1];
            else if (j == 2) v = bih[r] + bhh[r];
        } else if (s == 1) {     // Z
            int row = 64 + r;
            if (j == 0) v = Wih[2 * row];
            else if (j == 1) v = Wih[2 * row + 1];
            else if (j == 2) v = bih[row] + bhh[row];
        } else if (s == 2) {     // N (bhh_n only; r-scaled inside tanh arg)
            if (j == 2) v = bhh[128 + r];
        } else {                 // I (i_n = Wih_n . y + bih_n)
            int row = 128 + r;
            if (j == 0) v = Wih[2 * row];
            else if (j == 1) v = Wih[2 * row + 1];
            else if (j == 2) v = bih[row];
        }
        v *= (s < 2) ? SCL_RZ : SCL_NI;
    } else if (idx < OFF_W1F) {
        int i = idx - OFF_B1F;
        int mt = (i >> 6) & 1, ln = (i >> 2) & 15, j = i & 3;
        v = (j == 2) ? b1[mt * 16 + ln] : 0.f;       // unused in-kernel
    } else if (idx < OFF_W2F) {
        int i = idx - OFF_W1F;
        int fi = i >> 9, l = (i >> 3) & 63, j = i & 7;
        int mt = fi >> 1, ks = fi & 1;
        v = W1[(mt * 16 + (l & 15)) * 64 + ks * 32 + ((l >> 4) & 3) * 8 + j];
    } else {
        int i = idx - OFF_W2F;
        int l = (i >> 3) & 63, j = i & 7;
        int lnn = l & 15;
        v = (lnn < 4) ? W2[lnn * 32 + ((l >> 4) & 3) * 8 + j] : 0.f;
    }
    wsw[idx] = f2bf(v);
}

// ---------------- main kernel: 4 waves/block, 16 rows/wave, 3 blocks/CU ----------------
__global__ __launch_bounds__(256, 3)
void arflow12(const float* __restrict__ y_tm1,
              const float* __restrict__ z,
              const float* __restrict__ x,
              const float* __restrict__ b1,
              const float* __restrict__ b2,
              const short* __restrict__ wsw,
              float* __restrict__ out,
              int B, int T)
{
    __shared__ __align__(16) float XY[64 * XYW];      //  7168 B (x, overwritten by y)
    __shared__ __align__(16) short HL[4][16 * HLW];   // 13312 B (per-wave h + a)
    __shared__ __align__(16) short WTAB[WTAB_N];      // 15616 B (NF|KS2|B1F|W1F|W2F)

    const int tid  = threadIdx.x;
    const int wave = tid >> 6;
    const int lane = tid & 63;
    const int g    = lane >> 4;
    const int ln   = lane & 15;
    const bool g0  = (g == 0);
    const int base = blockIdx.x * 64;
    const int rows = (B - base < 64) ? (B - base) : 64;
    const int NF4  = T >> 1;   // float4s per x-row

    // ---- stage x -> XY (coalesced) ----
    {
        const float4* xg = reinterpret_cast<const float4*>(x) + (size_t)base * NF4;
        const int tot = 64 * NF4;
        for (int i = tid; i < tot; i += 256) {
            float4 v = (i < rows * NF4) ? xg[i] : make_float4(0.f, 0.f, 0.f, 0.f);
            int r = i / NF4, c = i - r * NF4;
            *reinterpret_cast<float4*>(&XY[r * XYW + c * 4]) = v;
        }
    }
    // ---- stage WTAB (contiguous, NF..end) ----
    {
        const uint4* src = reinterpret_cast<const uint4*>(wsw + OFF_NF);
        uint4* dst = reinterpret_cast<uint4*>(WTAB);
        for (int i = tid; i < WTAB_N / 8; i += 256) dst[i] = src[i];
    }

    // ---- R,Z weights -> VGPRs (64 regs) ----
    bf16x8 wR[4][2], wZ[4][2];
#pragma unroll
    for (int mg = 0; mg < 4; ++mg)
#pragma unroll
        for (int ks = 0; ks < 2; ++ks) {
            wR[mg][ks] = *reinterpret_cast<const bf16x8*>(wsw + ((      mg * 16 + ln) * 64 + ks * 32 + g * 8));
            wZ[mg][ks] = *reinterpret_cast<const bf16x8*>(wsw + ((64  + mg * 16 + ln) * 64 + ks * 32 + g * 8));
        }
    // W2 frag hoisted (loop-invariant, 4 regs)
    bf16x8 w2f = *reinterpret_cast<const bf16x8*>(wsw + OFF_W2F + lane * 8);

    // b1 in D-layout as MLP1 C-operand init (8 persistent regs)
    f32x4 b1q[2];
#pragma unroll
    for (int mt = 0; mt < 2; ++mt) {
        float4 tv = reinterpret_cast<const float4*>(b1)[mt * 4 + g];
        b1q[mt][0] = tv.x; b1q[mt][1] = tv.y; b1q[mt][2] = tv.z; b1q[mt][3] = tv.w;
    }

    const float b20 = b2[0], b21 = b2[1], b22 = b2[2], b23 = b2[3];
    const f32x4 Z0 = {0.f, 0.f, 0.f, 0.f};

    // ---- init h (bf16 -> LDS only) and y ----
    const int gr = base + wave * 16 + ln;
    const bool ok = gr < B;
    float2 y;
    short* hl = &HL[wave][0];
#pragma unroll
    for (int mg = 0; mg < 4; ++mg) {
        float4 zv = ok ? reinterpret_cast<const float4*>(z)[(size_t)gr * 16 + mg * 4 + g]
                       : make_float4(0.f, 0.f, 0.f, 0.f);
        uint2 pk;
        pk.x = cvtpk(zv.x, zv.y);
        pk.y = cvtpk(zv.z, zv.w);
        *reinterpret_cast<uint2*>(&hl[ln * HLW + mg * 16 + g * 4]) = pk;
    }
    y = ok ? reinterpret_cast<const float2*>(y_tm1)[gr] : make_float2(0.f, 0.f);

    bf16x8 hb[2];
#pragma unroll
    for (int ks = 0; ks < 2; ++ks)
        hb[ks] = *reinterpret_cast<const bf16x8*>(&hl[ln * HLW + ks * 32 + g * 8]);

    __syncthreads();

    const uint32_t onepk = g0 ? 0x00003F80u : 0u;   // bf16(1.0) at elem slot 2
    // volatile LDS frag pointers (keep reads in-loop, out of registers)
    const volatile bf16x8* nfq = reinterpret_cast<const volatile bf16x8*>(WTAB) + lane;                 // N frags
    const volatile u32x2*  k2q = reinterpret_cast<const volatile u32x2*>(WTAB + (OFF_KS2 - OFF_NF)) + ln;
    const volatile bf16x8* w1q = reinterpret_cast<const volatile bf16x8*>(WTAB + (OFF_W1F - OFF_NF)) + lane;

    for (int t = 0; t < T; ++t) {
        // ks2 B-frag: k=0..2 = [y.x, y.y, 1] on g==0 lanes, else 0
        bf16x8 yb;
        {
            uint32_t ypk = cvtpk(y.x, y.y);
            union { bf16x8 v; uint32_t u[4]; } yu;
            yu.u[0] = g0 ? ypk : 0u;
            yu.u[1] = onepk;
            yu.u[2] = 0u; yu.u[3] = 0u;
            yb = yu.v;
        }

        // ---- GRU ----
#pragma unroll
        for (int mg = 0; mg < 4; ++mg) {
            // ks2 frags built sequentially: one live quad at a time
            f32x4 aR = __builtin_amdgcn_mfma_f32_16x16x32_bf16(fraglo(k2q[(0 * 4 + mg) * 16]), yb, Z0, 0, 0, 0);
            f32x4 aZ = __builtin_amdgcn_mfma_f32_16x16x32_bf16(fraglo(k2q[(1 * 4 + mg) * 16]), yb, Z0, 0, 0, 0);
            f32x4 aN = __builtin_amdgcn_mfma_f32_16x16x32_bf16(fraglo(k2q[(2 * 4 + mg) * 16]), yb, Z0, 0, 0, 0);
            f32x4 aI = __builtin_amdgcn_mfma_f32_16x16x32_bf16(fraglo(k2q[(3 * 4 + mg) * 16]), yb, Z0, 0, 0, 0);
            aR = __builtin_amdgcn_mfma_f32_16x16x32_bf16(wR[mg][0], hb[0], aR, 0, 0, 0);
            aZ = __builtin_amdgcn_mfma_f32_16x16x32_bf16(wZ[mg][0], hb[0], aZ, 0, 0, 0);
            aN = __builtin_amdgcn_mfma_f32_16x16x32_bf16(nfq[(mg * 2 + 0) * 64], hb[0], aN, 0, 0, 0);
            aR = __builtin_amdgcn_mfma_f32_16x16x32_bf16(wR[mg][1], hb[1], aR, 0, 0, 0);
            aZ = __builtin_amdgcn_mfma_f32_16x16x32_bf16(wZ[mg][1], hb[1], aZ, 0, 0, 0);
            aN = __builtin_amdgcn_mfma_f32_16x16x32_bf16(nfq[(mg * 2 + 1) * 64], hb[1], aN, 0, 0, 0);

            // old h (bf16, this lane's own D-layout quad) from LDS
            u32x2 oh = *reinterpret_cast<const u32x2*>(&hl[ln * HLW + mg * 16 + g * 4]);
            float hold[4];
            hold[0] = bflo(oh[0]); hold[1] = bfhi(oh[0]);
            hold[2] = bflo(oh[1]); hold[3] = bfhi(oh[1]);

            float hq[4];
#pragma unroll
            for (int q = 0; q < 4; ++q) {
                float r  = rcpf(1.f + exp2f(aR[q]));
                float u  = rcpf(1.f + exp2f(aZ[q]));
                float ee = exp2f(fmaf(r, aN[q], aI[q]));
                float nn = fmaf(-2.f, rcpf(ee + 1.f), 1.f);
                hq[q] = fmaf(u, hold[q] - nn, nn);   // (1-u)*n + u*h
            }
            uint2 pk;
            pk.x = cvtpk(hq[0], hq[1]);
            pk.y = cvtpk(hq[2], hq[3]);
            *reinterpret_cast<uint2*>(&hl[ln * HLW + mg * 16 + g * 4]) = pk;
        }

        // ---- re-read h' B-frags (MLP1 now, GRU next step) ----
        hb[0] = *reinterpret_cast<const bf16x8*>(&hl[ln * HLW +  0 + g * 8]);
        hb[1] = *reinterpret_cast<const bf16x8*>(&hl[ln * HLW + 32 + g * 8]);

        // ---- MLP1 via MFMA (b1 as C-operand init) ----
        f32x4 aM[2];
#pragma unroll
        for (int mt = 0; mt < 2; ++mt) {
            bf16x8 w0 = w1q[(mt * 2 + 0) * 64];
            bf16x8 w1 = w1q[(mt * 2 + 1) * 64];
            f32x4 a = __builtin_amdgcn_mfma_f32_16x16x32_bf16(w0, hb[0], b1q[mt], 0, 0, 0);
            aM[mt] = __builtin_amdgcn_mfma_f32_16x16x32_bf16(w1, hb[1], a, 0, 0, 0);
        }

        // ---- relu(a) -> hl cols 64..95, MLP2 via padded MFMA ----
#pragma unroll
        for (int mt = 0; mt < 2; ++mt) {
            uint2 pk;
            pk.x = cvtpk(fmaxf(aM[mt][0], 0.f), fmaxf(aM[mt][1], 0.f));
            pk.y = cvtpk(fmaxf(aM[mt][2], 0.f), fmaxf(aM[mt][3], 0.f));
            *reinterpret_cast<uint2*>(&hl[ln * HLW + 64 + mt * 16 + g * 4]) = pk;
        }
        f32x4 aD;
        {
            bf16x8 ab = *reinterpret_cast<const bf16x8*>(&hl[ln * HLW + 64 + g * 8]);
            aD = __builtin_amdgcn_mfma_f32_16x16x32_bf16(w2f, ab, Z0, 0, 0, 0);
        }

        // ---- flow update (aD valid on g==0; 0 on g>0 so y stays finite) ----
        {
            int rl = wave * 16 + ln;
            float2 xt = *reinterpret_cast<const float2*>(&XY[rl * XYW + t * 2]);
            float s0 = softplusf(aD[2] + b22) + 1e-6f;
            float s1 = softplusf(aD[3] + b23) + 1e-6f;
            y.x += (aD[0] + b20) + s0 * xt.x;
            y.y += (aD[1] + b21) + s1 * xt.y;
            if (g0)
                *reinterpret_cast<float2*>(&XY[rl * XYW + t * 2]) = y;
        }
    }

    __syncthreads();
    // ---- coalesced store XY -> out ----
    {
        float4* og = reinterpret_cast<float4*>(out) + (size_t)base * NF4;
        const int tot = 64 * NF4;
        for (int i = tid; i < tot; i += 256) {
            if (i < rows * NF4) {
                int r = i / NF4, c = i - r * NF4;
                og[i] = *reinterpret_cast<const float4*>(&XY[r * XYW + c * 4]);
            }
        }
    }
}

extern "C" void kernel_launch(void* const* d_in, const int* in_sizes, int n_in,
                              void* d_out, int out_size, void* d_ws, size_t ws_size,
                              hipStream_t stream) {
    const float* y_tm1 = (const float*)d_in[0];
    const float* z     = (const float*)d_in[1];
    const float* x     = (const float*)d_in[2];
    const float* Wih   = (const float*)d_in[3];
    const float* Whh   = (const float*)d_in[4];
    const float* bih   = (const float*)d_in[5];
    const float* bhh   = (const float*)d_in[6];
    const float* W1    = (const float*)d_in[7];
    const float* b1    = (const float*)d_in[8];
    const float* W2    = (const float*)d_in[9];
    const float* b2    = (const float*)d_in[10];
    float* out = (float*)d_out;
    short* wsw = (short*)d_ws;

    const int B = in_sizes[0] / 2;
    const int T = in_sizes[2] / in_sizes[0];

    hipLaunchKernelGGL(prep_kernel, dim3((WS_TOT + 255) / 256), dim3(256), 0, stream,
                       Wih, Whh, bih, bhh, W1, W2, b1, wsw);

    const int nblk = (B + 63) / 64;
    hipLaunchKernelGGL(arflow12, dim3(nblk), dim3(256), 0, stream,
                       y_tm1, z, x, b1, b2, wsw, out, B, T);
}